// Round 8
// baseline (505.443 us; speedup 1.0000x reference)
//
#include <hip/hip_runtime.h>
#include <hip/hip_bf16.h>

#define NB 128
#define NP 8732
#define NO 32
#define NC 21
#define NCH 8
#define CH 1152    // priors per chunk; 7*1152 + 668 = 8732
#define NPB ((NP + 255) / 256)   // 35 chunk-blocks per image in k_loss

// ---------------- workspace layout ----------------
// [0, 262144)        : unsigned long long packed2[NB][NO][NCH]  (plain stores)
// [262144, 262656)   : int npos[NB]
// [262656, 265728)   : double accb[NB][3]  (0=pos_conf, 1=loc, 2=hard_neg)
// [265728, 265732)   : int flag (global last-image ticket)
// [265984, 266496)   : int imgcnt[NB] (per-image last-block ticket)
// [266496, +NB*NP*4) : int code[NB*NP]   (obj | matched<<8)
// [..., +NB*NP*4)    : float confneg[NB*NP]

// Each IoU computed ONCE, feeding both argmax directions.
// Grid (NCH, NB) x 256 thr; 4 waves x 8 objects; priors chunk in LDS (xyxy).
// Per-object dir: register u64 keys -> wave reduce -> plain store to packed2.
// Per-prior dir: wave best-of-8 -> LDS u64 atomicMax across 4 waves -> code[].
__global__ __launch_bounds__(256) void k_match(const float* __restrict__ boxes,
                                               const float* __restrict__ priors,
                                               unsigned long long* __restrict__ packed2,
                                               int* __restrict__ code,
                                               int* __restrict__ npos,
                                               double* __restrict__ accb,
                                               int* __restrict__ flag,
                                               int* __restrict__ imgcnt) {
    __shared__ float4 spri[CH];                 // 18432 B
    __shared__ unsigned long long skey[CH];     // 9216 B
    __shared__ float4 sbox[NO];
    const int ch = blockIdx.x, b = blockIdx.y, tid = threadIdx.x;
    const int lane = tid & 63, wid = tid >> 6;  // 4 waves
    const int pbeg = ch * CH;
    const int n = min(CH, NP - pbeg);           // 1152 or 668

    if (ch == 0) {
        if (tid == 0) npos[b] = 0;
        if (tid >= 1 && tid <= 3) accb[b * 3 + (tid - 1)] = 0.0;
        if (tid == 4) imgcnt[b] = 0;
        if (b == 0 && tid == 5) *flag = 0;
    }
    if (tid < NO) sbox[tid] = ((const float4*)boxes)[b * NO + tid];
    for (int i = tid; i < n; i += 256) {
        float4 pr = ((const float4*)priors)[pbeg + i];
        spri[i] = make_float4(pr.x - pr.z * 0.5f, pr.y - pr.w * 0.5f,
                              pr.x + pr.z * 0.5f, pr.y + pr.w * 0.5f);
        skey[i] = 0ull;
    }
    __syncthreads();

    // wave's 8 boxes hoisted to registers
    float bxx[8], bxy[8], bxz[8], bxw[8], a1[8];
#pragma unroll
    for (int oo = 0; oo < 8; ++oo) {
        float4 bx = sbox[wid * 8 + oo];
        bxx[oo] = bx.x; bxy[oo] = bx.y; bxz[oo] = bx.z; bxw[oo] = bx.w;
        a1[oo] = (bx.z - bx.x) * (bx.w - bx.y);
    }
    unsigned long long okey[8] = {0ull,0ull,0ull,0ull,0ull,0ull,0ull,0ull};

    for (int i = lane; i < n; i += 64) {
        float4 pr = spri[i];
        float pa = (pr.z - pr.x) * (pr.w - pr.y);
        const unsigned long long inv_p =
            (unsigned long long)(0xFFFFFFFFu - (unsigned)(pbeg + i));
        unsigned long long pkey = 0ull;
#pragma unroll
        for (int oo = 0; oo < 8; ++oo) {
            float lx = fmaxf(bxx[oo], pr.x), ly = fmaxf(bxy[oo], pr.y);
            float hx = fminf(bxz[oo], pr.z), hy = fminf(bxw[oo], pr.w);
            float iw = fmaxf(hx - lx, 0.0f), ih = fmaxf(hy - ly, 0.0f);
            float inter = iw * ih;
            float iou = inter / (a1[oo] + pa - inter);
            unsigned long long base = ((unsigned long long)__float_as_uint(iou) << 32);
            // object dir: larger iou, tie -> smaller p
            unsigned long long ko = base | inv_p;
            if (ko > okey[oo]) okey[oo] = ko;
            // prior dir: larger iou, tie -> smaller o (first-max, jnp.argmax axis=0)
            unsigned long long kp = base | (unsigned)(NO - 1 - (wid * 8 + oo));
            if (kp > pkey) pkey = kp;
        }
        atomicMax(&skey[i], pkey);
    }
#pragma unroll
    for (int oo = 0; oo < 8; ++oo) {
        unsigned long long pk = okey[oo];
        for (int s = 32; s > 0; s >>= 1) {
            unsigned long long t = __shfl_xor(pk, s, 64);
            if (t > pk) pk = t;
        }
        if (lane == 0) packed2[(b * NO + wid * 8 + oo) * NCH + ch] = pk;
    }
    __syncthreads();
    for (int i = tid; i < n; i += 256) {
        unsigned long long k = skey[i];
        int o = NO - 1 - (int)(unsigned)(k & 0xFFFFFFFFull);
        float bv = __uint_as_float((unsigned)(k >> 32));
        code[(size_t)b * NP + pbeg + i] = o | (bv >= 0.5f ? 256 : 0);
    }
}

// Per-prior losses + per-image topk (last chunk block) + global final (last image).
__global__ __launch_bounds__(256) void k_loss(const float* __restrict__ plocs,
                                              const float* __restrict__ scores,
                                              const float* __restrict__ boxes,
                                              const int* __restrict__ labels,
                                              const float* __restrict__ priors,
                                              const unsigned long long* __restrict__ packed2,
                                              const int* __restrict__ code,
                                              float* __restrict__ confneg,
                                              int* __restrict__ npos,
                                              double* __restrict__ accb,
                                              int* __restrict__ flag,
                                              int* __restrict__ imgcnt,
                                              float* __restrict__ out) {
    __shared__ float srow[256 * NC];  // 21504 B
    __shared__ float4 sbox[NO];
    __shared__ int sfp[NO];
    __shared__ int slab[NO];
    __shared__ float w0[4], w1[4];
    __shared__ int wc[4];
    __shared__ int si[2][4];
    __shared__ double sd[8];
    __shared__ int sElect, sFinal;
    const int b = blockIdx.y, tid = threadIdx.x;
    const int p0 = blockIdx.x * 256;
    const int cnt = min(256, NP - p0);  // 256 or 28; cnt*21 % 4 == 0
    const int wid = tid >> 6, lane = tid & 63;

    // forced-match prior per object: reduce packed2 over 8 chunks (tid = o*8+ch)
    {
        unsigned long long key = packed2[b * (NO * NCH) + tid];
#pragma unroll
        for (int s = 1; s < 8; s <<= 1) {
            unsigned long long t = __shfl_xor(key, s, 64);
            if (t > key) key = t;
        }
        if ((tid & 7) == 0)
            sfp[tid >> 3] = (int)(0xFFFFFFFFu - (unsigned)(key & 0xFFFFFFFFull));
    }
    if (tid < NO) {
        sbox[tid] = ((const float4*)boxes)[b * NO + tid];
        slab[tid] = labels[b * NO + tid];
    }
    const int nf4 = cnt * NC / 4;
    const float4* src4 = (const float4*)(scores + ((size_t)b * NP + p0) * NC);
    for (int i = tid; i < nf4; i += 256) ((float4*)srow)[i] = src4[i];
    __syncthreads();

    float posconf = 0.0f, locpart = 0.0f;
    int isp = 0;

    if (tid < cnt) {
        const int p = p0 + tid;
        int cd = code[(size_t)b * NP + p];
        int obj = cd & 255;
        int matched = (cd >> 8) & 1;
        int ovr = -1;
#pragma unroll
        for (int o = 0; o < NO; ++o)
            if (sfp[o] == p) ovr = o;  // ascending: last o wins (numpy scatter)
        if (ovr >= 0) { obj = ovr; matched = 1; }
        int lbl = matched ? slab[obj] : 0;

        const float* s = srow + tid * NC;  // stride 21: conflict-free
        float m = s[0];
#pragma unroll
        for (int c = 1; c < NC; ++c) m = fmaxf(m, s[c]);
        float sum = 0.0f;
#pragma unroll
        for (int c = 0; c < NC; ++c) sum += __expf(s[c] - m);
        float conf = m + __logf(sum) - s[lbl];

        if (lbl != 0) {
            isp = 1;
            posconf = conf;
            float4 pr = ((const float4*)priors)[p];
            float4 bx = sbox[obj];
            float cx = (bx.x + bx.z) * 0.5f, cy = (bx.y + bx.w) * 0.5f;
            float w = bx.z - bx.x, h = bx.w - bx.y;
            float gx = (cx - pr.x) / (pr.z * 0.1f);
            float gy = (cy - pr.y) / (pr.w * 0.1f);
            float gw = __logf(w / pr.z) * 5.0f;
            float gh = __logf(h / pr.w) * 5.0f;
            float4 pl = ((const float4*)plocs)[(size_t)b * NP + p];
            locpart = fabsf(pl.x - gx) + fabsf(pl.y - gy) +
                      fabsf(pl.z - gw) + fabsf(pl.w - gh);
        }
        confneg[(size_t)b * NP + p] = isp ? 0.0f : conf;
    }

    for (int s = 32; s > 0; s >>= 1) {
        posconf += __shfl_xor(posconf, s, 64);
        locpart += __shfl_xor(locpart, s, 64);
        isp     += __shfl_xor(isp, s, 64);
    }
    if (lane == 0) { w0[wid] = posconf; w1[wid] = locpart; wc[wid] = isp; }
    __syncthreads();
    if (tid == 0) {
        atomicAdd(&npos[b], wc[0] + wc[1] + wc[2] + wc[3]);
        atomicAdd(&accb[b * 3 + 0], (double)(w0[0] + w0[1] + w0[2] + w0[3]));
        atomicAdd(&accb[b * 3 + 1], (double)(w1[0] + w1[1] + w1[2] + w1[3]));
        __threadfence();
        int t = atomicAdd(&imgcnt[b], 1);
        sElect = (t == NPB - 1) ? 1 : 0;
    }
    __syncthreads();

    if (sElect) {  // block-uniform: this image's last chunk block does the top-k
        __threadfence();
        const float* src = confneg + (size_t)b * NP;
        float val[35];
#pragma unroll
        for (int j = 0; j < 35; ++j) {
            int i = tid + j * 256;
            val[j] = (i < NP) ? src[i] : 0.0f;  // 0 never counts (cand > 0)
        }
        int k = npos[b] * 3;
        if (k > NP) k = NP;
        if (k > 0) {  // block-uniform
            unsigned T = 0;
            for (int bit = 30; bit >= 0; --bit) {
                unsigned cand = T | (1u << bit);
                int c2 = 0;
#pragma unroll
                for (int j = 0; j < 35; ++j)
                    c2 += (__float_as_uint(val[j]) >= cand) ? 1 : 0;
                for (int s = 32; s > 0; s >>= 1) c2 += __shfl_xor(c2, s, 64);
                if (lane == 0) si[bit & 1][wid] = c2;
                __syncthreads();
                int tot = si[bit & 1][0] + si[bit & 1][1] + si[bit & 1][2] + si[bit & 1][3];
                if (tot >= k) T = cand;  // uniform decision (double-buffered)
            }
            int cgt = 0;
            double sgt = 0.0;
#pragma unroll
            for (int j = 0; j < 35; ++j) {
                unsigned u = __float_as_uint(val[j]);
                if (u > T) { cgt++; sgt += (double)val[j]; }
            }
            for (int s = 32; s > 0; s >>= 1) {
                cgt += __shfl_xor(cgt, s, 64);
                sgt += __shfl_xor(sgt, s, 64);
            }
            __syncthreads();  // protect si reuse vs last bisection reads
            if (lane == 0) { si[0][wid] = cgt; sd[wid] = sgt; }
            __syncthreads();
            if (tid == 0) {
                int cg = si[0][0] + si[0][1] + si[0][2] + si[0][3];
                double sg = sd[0] + sd[1] + sd[2] + sd[3];
                accb[b * 3 + 2] = sg + (double)(k - cg) * (double)__uint_as_float(T);
            }
        }
        // accb[b*3+2] stays 0 (zeroed by k_match) when k == 0.

        if (tid == 0) {
            __threadfence();
            int t2 = atomicAdd(flag, 1);
            sFinal = (t2 == NB - 1) ? 1 : 0;
        }
        __syncthreads();
        if (sFinal) {  // globally last image: final scalar
            __threadfence();
            double pc = 0, lc = 0, hn = 0, nn = 0;
            if (tid < NB) {
                pc = accb[tid * 3 + 0];
                lc = accb[tid * 3 + 1];
                hn = accb[tid * 3 + 2];
                nn = (double)npos[tid];
            }
            if (tid < 128) {  // 2 waves
                for (int s = 32; s > 0; s >>= 1) {
                    pc += __shfl_xor(pc, s, 64);
                    lc += __shfl_xor(lc, s, 64);
                    hn += __shfl_xor(hn, s, 64);
                    nn += __shfl_xor(nn, s, 64);
                }
                if (lane == 0) { sd[wid * 4 + 0] = pc; sd[wid * 4 + 1] = lc;
                                 sd[wid * 4 + 2] = hn; sd[wid * 4 + 3] = nn; }
            }
            __syncthreads();
            if (tid == 0) {
                double P  = sd[0] + sd[4];
                double L  = sd[1] + sd[5];
                double H  = sd[2] + sd[6];
                double NT = sd[3] + sd[7];
                out[0] = (float)((H + P) / NT + L / (NT * 4.0));
            }
        }
    }
}

extern "C" void kernel_launch(void* const* d_in, const int* in_sizes, int n_in,
                              void* d_out, int out_size, void* d_ws, size_t ws_size,
                              hipStream_t stream) {
    const float* plocs  = (const float*)d_in[0];
    const float* scores = (const float*)d_in[1];
    const float* boxes  = (const float*)d_in[2];
    const int*   labels = (const int*)d_in[3];
    const float* priors = (const float*)d_in[4];
    float* out = (float*)d_out;

    char* ws = (char*)d_ws;
    unsigned long long* packed2 = (unsigned long long*)ws;
    int*    npos    = (int*)(ws + 262144);
    double* accb    = (double*)(ws + 262656);
    int*    flag    = (int*)(ws + 265728);
    int*    imgcnt  = (int*)(ws + 265984);
    int*    code    = (int*)(ws + 266496);
    float*  confneg = (float*)(ws + 266496 + (size_t)NB * NP * 4);

    hipLaunchKernelGGL(k_match, dim3(NCH, NB), dim3(256), 0, stream,
                       boxes, priors, packed2, code, npos, accb, flag, imgcnt);
    hipLaunchKernelGGL(k_loss, dim3(NPB, NB), dim3(256), 0, stream,
                       plocs, scores, boxes, labels, priors, packed2, code,
                       confneg, npos, accb, flag, imgcnt, out);
}